// Round 9
// baseline (56.537 us; speedup 1.0000x reference)
//
#include <hip/hip_runtime.h>
#include <utility>

// Geometric product in Cl(3,2,1), DIM=64.
// out[n,k] = sum_a sign(a, a^k) * x[n,a] * y[n,a^k]
//
// ROUND 9: async pipeline. T=4 tiles/block, grid 256 (1 block/CU).
// Staging via __builtin_amdgcn_global_load_lds(16B) with XOR-pre-swizzled
// per-lane GLOBAL source (LDS dest must be linear): LDS[r][p] = global
// granule p^(r&15). Compute reads row r as 16 b128 granule loads at
// position g^(r&15): 8 lanes/bank-quad = conflict-free. Rows live in
// registers (xv[64]/yv[64], constant-index template core = promotion-proven).
// Raw s_barrier + counted s_waitcnt vmcnt(8) (never 0 mid-loop) keep the
// next tile's loads in flight across barriers -- the mechanism
// __syncthreads() structurally defeats (compiler drains vmcnt(0)).
// Output transpose reuses the dead compute buffer; LDS = 2 x 32 KB.

__host__ __device__ constexpr int popc6(int v) {
  int c = 0;
  for (int i = 0; i < 6; ++i) c += (v >> i) & 1;
  return c;
}

// Faithful to reference _cayley_tables(3,2,1): swap parity, (-1) per shared
// negative dim (bits 3,4), annihilation on shared null dim (bit 5).
__host__ __device__ constexpr float sign_ab(int a, int b) {
  int sw = 0;
  for (int bit = 0; bit < 6; ++bit)
    if ((a >> bit) & 1) sw += popc6(b & ((1 << bit) - 1));
  float s = (sw & 1) ? -1.0f : 1.0f;
  if (popc6(a & b & 0x18) & 1) s = -s;
  if (a & b & 0x20) s = 0.0f;
  return s;
}

// ---- compile-time FMA core: constant indices only (promotion-safe) ----
template <int Q, int A, int KK>
__device__ __forceinline__ void term(const float (&xv)[64], const float (&yv)[64],
                                     float (&acc)[16]) {
  constexpr int k = 4 * KK + Q;
  constexpr int b = A ^ k;
  constexpr float sg = sign_ab(A, b);
  if constexpr (sg > 0.0f)      acc[KK] = fmaf( xv[A], yv[b], acc[KK]);
  else if constexpr (sg < 0.0f) acc[KK] = fmaf(-xv[A], yv[b], acc[KK]);
}

template <int Q, int A, int... KK>
__device__ __forceinline__ void terms(const float (&xv)[64], const float (&yv)[64],
                                      float (&acc)[16], std::integer_sequence<int, KK...>) {
  (term<Q, A, KK>(xv, yv, acc), ...);
}

template <int Q, int... A>
__device__ __forceinline__ void all_a(const float (&xv)[64], const float (&yv)[64],
                                      float (&acc)[16], std::integer_sequence<int, A...>) {
  (terms<Q, A>(xv, yv, acc, std::make_integer_sequence<int, 16>{}), ...);
}

// Pull row `lane` of x and y from the swizzled LDS tile into registers,
// then run the 768-FMA constant-sign core.
template <int Q>
__device__ __forceinline__ void core(const float4* __restrict__ buf, int lane,
                                     float (&acc)[16]) {
  const float4* xt = buf;          // x rows: f4 [0,1024)
  const float4* yt = buf + 1024;   // y rows: f4 [1024,2048)
  const int rbase = lane * 16;
  const int sw = lane & 15;
  float xv[64], yv[64];
#pragma unroll
  for (int g = 0; g < 16; ++g) {
    const float4 fx = xt[rbase + (g ^ sw)];  // conflict-free b128
    const float4 fy = yt[rbase + (g ^ sw)];
    xv[4 * g + 0] = fx.x; xv[4 * g + 1] = fx.y; xv[4 * g + 2] = fx.z; xv[4 * g + 3] = fx.w;
    yv[4 * g + 0] = fy.x; yv[4 * g + 1] = fy.y; yv[4 * g + 2] = fy.z; yv[4 * g + 3] = fy.w;
  }
  all_a<Q>(xv, yv, acc, std::make_integer_sequence<int, 64>{});
}

typedef __attribute__((address_space(3))) unsigned int lds_u32;
typedef __attribute__((address_space(1))) const unsigned int glb_u32;

__device__ __forceinline__ void load16(const void* g, void* l) {
  __builtin_amdgcn_global_load_lds((glb_u32*)g, (lds_u32*)l, 16, 0, 0);
}

// Stage one 64x64 tile of x and y into `buf` (x: rows*16 f4, y: +1024).
// Wave q stages rows [16q, 16q+16): 4 instructions each for x and y.
// Per-lane global source is XOR-pre-swizzled; LDS dest is linear
// (wave-uniform base + lane*16B, per HW).
__device__ __forceinline__ void stage(const float* __restrict__ xg,
                                      const float* __restrict__ yg,
                                      float4* __restrict__ buf, int lane, int q) {
#pragma unroll
  for (int i = 0; i < 4; ++i) {
    const int rb = 16 * q + 4 * i;            // wave-uniform row block (4 rows)
    const int r = rb + (lane >> 4);           // this lane's row
    const int gsw = (lane & 15) ^ (r & 15);   // swizzled source granule
    load16(xg + r * 64 + gsw * 4, (char*)(buf) + rb * 256);
    load16(yg + r * 64 + gsw * 4, (char*)(buf + 1024) + rb * 256);
  }
}

__global__ __launch_bounds__(256, 2)
void clgp_kernel(const float* __restrict__ xg, const float* __restrict__ yg,
                 float* __restrict__ og) {
  __shared__ float4 bufA[2048];  // 32 KB: x tile + y tile (swizzled rows)
  __shared__ float4 bufB[2048];

  const int t = threadIdx.x;
  const int lane = t & 63;
  const int q = t >> 6;                        // wave id = k mod 4 class
  const long base = (long)blockIdx.x * 4 * 4096;  // 4 tiles of 64x64 floats

  // prologue: stage tile 0 into bufA (8 loads/wave in flight)
  stage(xg + base, yg + base, bufA, lane, q);

#pragma unroll 1
  for (int u = 0; u < 4; ++u) {
    float4* bcur = (u & 1) ? bufB : bufA;
    float4* bnxt = (u & 1) ? bufA : bufB;

    // B0: previous iter's LDS reads (store path) done before bnxt is re-staged
    __builtin_amdgcn_s_barrier();
    if (u < 3) {
      const long nbase = base + (long)(u + 1) * 4096;
      stage(xg + nbase, yg + nbase, bnxt, lane, q);  // async, stays in flight
      asm volatile("s_waitcnt vmcnt(8)" ::: "memory");  // tile u landed; u+1 in flight
    } else {
      asm volatile("s_waitcnt vmcnt(0)" ::: "memory");
    }
    __builtin_amdgcn_sched_barrier(0);
    // B1: all waves' stage of tile u visible to everyone
    __builtin_amdgcn_s_barrier();

    float acc[16];
#pragma unroll
    for (int i = 0; i < 16; ++i) acc[i] = 0.0f;
    switch (q) {  // wave-uniform
      case 0:  core<0>(bcur, lane, acc); break;
      case 1:  core<1>(bcur, lane, acc); break;
      case 2:  core<2>(bcur, lane, acc); break;
      default: core<3>(bcur, lane, acc); break;
    }
    __builtin_amdgcn_sched_barrier(0);
    // B2: all compute reads of bcur done -> bcur reusable as obuf
    __builtin_amdgcn_s_barrier();

    float* ob = (float*)bcur;  // 64x65 transpose area (16.6 KB < 32 KB)
#pragma unroll
    for (int kk = 0; kk < 16; ++kk) ob[lane * 65 + 4 * kk + q] = acc[kk];
    asm volatile("s_waitcnt lgkmcnt(0)" ::: "memory");
    __builtin_amdgcn_sched_barrier(0);
    // B3: transpose complete
    __builtin_amdgcn_s_barrier();

    float4* o4 = (float4*)(og + base + (long)u * 4096);
#pragma unroll
    for (int p = 0; p < 4; ++p) {
      const int v = t + p * 256;
      const int w = (v >> 4) * 65 + 4 * (v & 15);
      float4 o;
      o.x = ob[w + 0]; o.y = ob[w + 1]; o.z = ob[w + 2]; o.w = ob[w + 3];
      o4[v] = o;
    }
  }
}

extern "C" void kernel_launch(void* const* d_in, const int* in_sizes, int n_in,
                              void* d_out, int out_size, void* d_ws, size_t ws_size,
                              hipStream_t stream) {
  const float* x = (const float*)d_in[0];
  const float* y = (const float*)d_in[1];
  float* out = (float*)d_out;
  const int n_batch = in_sizes[0] / 64;        // 65536
  const int grid = n_batch / (64 * 4);         // 4 tiles/block -> 256 blocks
  clgp_kernel<<<grid, 256, 0, stream>>>(x, y, out);
}

// Round 10
// 23.674 us; speedup vs baseline: 2.3881x; 2.3881x over previous
//
#include <hip/hip_runtime.h>
#include <utility>

// Geometric product in Cl(3,2,1), DIM=64.
// out[n,k] = sum_a sign(a, a^k) * x[n,a] * y[n,a^k]
//
// ROUND 10: spill-free streaming kernel. 16-float block decomposition:
//   k = 16q + j, a = 16m + i  =>  b = a^k = 16*(m^q) + (i^j)
// Thread = (row n, k-quarter q): for each m-block, load x16[m] and
// y16[m^q] (4+4 f4 loads, constant offsets), do 256 constant-sign FMAs
// acc[j] += s * x16[i] * y16[i^j]. Null-dim: q<2 => only m<2 live (512
// FMA); q>=2 => all m, no zeros (1024 FMA). Peak live regs ~90 (acc16 +
// x16 + y16 + next-m in flight) -- no spill at the 128 cap (R9's failure:
// 160 live -> spill; R1-R3: failed SROA -> scratch). No LDS, no barriers,
// 64B-contiguous stores per thread (L2 merges 4 q-threads per line).
// q rotated by blockIdx so 512-FMA and 1024-FMA waves balance across SIMDs.

__host__ __device__ constexpr int popc6(int v) {
  int c = 0;
  for (int i = 0; i < 6; ++i) c += (v >> i) & 1;
  return c;
}

// Faithful to reference _cayley_tables(3,2,1): swap parity, (-1) per shared
// negative dim (bits 3,4), annihilation on shared null dim (bit 5).
__host__ __device__ constexpr float sign_ab(int a, int b) {
  int sw = 0;
  for (int bit = 0; bit < 6; ++bit)
    if ((a >> bit) & 1) sw += popc6(b & ((1 << bit) - 1));
  float s = (sw & 1) ? -1.0f : 1.0f;
  if (popc6(a & b & 0x18) & 1) s = -s;
  if (a & b & 0x20) s = 0.0f;
  return s;
}

// ---- compile-time FMA core: constant indices only (promotion-safe) ----
template <int Q, int M, int I, int J>
__device__ __forceinline__ void term(const float (&xv)[16], const float (&yv)[16],
                                     float (&acc)[16]) {
  constexpr int a = 16 * M + I;
  constexpr int k = 16 * Q + J;
  constexpr float sg = sign_ab(a, a ^ k);
  static_assert(sg != 0.0f, "zero terms must be excluded by M-list");
  if constexpr (sg > 0.0f) acc[J] = fmaf( xv[I], yv[I ^ J], acc[J]);
  else                     acc[J] = fmaf(-xv[I], yv[I ^ J], acc[J]);
}

template <int Q, int M, int I, int... J>
__device__ __forceinline__ void terms(const float (&xv)[16], const float (&yv)[16],
                                      float (&acc)[16], std::integer_sequence<int, J...>) {
  (term<Q, M, I, J>(xv, yv, acc), ...);
}

template <int Q, int M, int... I>
__device__ __forceinline__ void block_fma(const float (&xv)[16], const float (&yv)[16],
                                          float (&acc)[16], std::integer_sequence<int, I...>) {
  (terms<Q, M, I>(xv, yv, acc, std::make_integer_sequence<int, 16>{}), ...);
}

// One m-block: load x16[M] and y16[M^Q] (constant f4 offsets), 256 FMAs.
template <int Q, int M>
__device__ __forceinline__ void group(const float4* __restrict__ x4,
                                      const float4* __restrict__ y4, float (&acc)[16]) {
  float xv[16], yv[16];
#pragma unroll
  for (int u = 0; u < 4; ++u) {
    const float4 fx = x4[4 * M + u];
    const float4 fy = y4[4 * (M ^ Q) + u];
    xv[4 * u + 0] = fx.x; xv[4 * u + 1] = fx.y; xv[4 * u + 2] = fx.z; xv[4 * u + 3] = fx.w;
    yv[4 * u + 0] = fy.x; yv[4 * u + 1] = fy.y; yv[4 * u + 2] = fy.z; yv[4 * u + 3] = fy.w;
  }
  block_fma<Q, M>(xv, yv, acc, std::make_integer_sequence<int, 16>{});
}

template <int Q>
__device__ __forceinline__ void compute(const float4* __restrict__ x4,
                                        const float4* __restrict__ y4, float (&acc)[16]) {
  group<Q, 0>(x4, y4, acc);
  group<Q, 1>(x4, y4, acc);
  if constexpr (Q >= 2) {  // q<2: a>=32 annihilates (null dim) -> skip m=2,3
    group<Q, 2>(x4, y4, acc);
    group<Q, 3>(x4, y4, acc);
  }
}

__global__ __launch_bounds__(256, 4)
void clgp_kernel(const float* __restrict__ xg, const float* __restrict__ yg,
                 float* __restrict__ og) {
  const int t = threadIdx.x;
  const int lane = t & 63;                       // row within block
  const int q = ((t >> 6) + blockIdx.x) & 3;     // k-quarter, rotated for SIMD balance
  const long n = (long)blockIdx.x * 64 + lane;
  const float4* x4 = (const float4*)(xg + n * 64);
  const float4* y4 = (const float4*)(yg + n * 64);

  float acc[16];
#pragma unroll
  for (int i = 0; i < 16; ++i) acc[i] = 0.0f;

  switch (q) {  // wave-uniform (t>>6 and blockIdx are uniform per wave)
    case 0:  compute<0>(x4, y4, acc); break;
    case 1:  compute<1>(x4, y4, acc); break;
    case 2:  compute<2>(x4, y4, acc); break;
    default: compute<3>(x4, y4, acc); break;
  }

  // 64B contiguous store of this thread's k-quarter
  float4* o4 = (float4*)(og + n * 64 + 16 * q);
#pragma unroll
  for (int j = 0; j < 4; ++j) {
    float4 o;
    o.x = acc[4 * j + 0]; o.y = acc[4 * j + 1]; o.z = acc[4 * j + 2]; o.w = acc[4 * j + 3];
    o4[j] = o;
  }
}

extern "C" void kernel_launch(void* const* d_in, const int* in_sizes, int n_in,
                              void* d_out, int out_size, void* d_ws, size_t ws_size,
                              hipStream_t stream) {
  const float* x = (const float*)d_in[0];
  const float* y = (const float*)d_in[1];
  float* out = (float*)d_out;
  const int n_batch = in_sizes[0] / 64;   // 65536
  const int grid = n_batch / 64;          // 1024 blocks of 256 threads
  clgp_kernel<<<grid, 256, 0, stream>>>(x, y, out);
}

// Round 11
// 20.036 us; speedup vs baseline: 2.8218x; 1.1816x over previous
//
#include <hip/hip_runtime.h>
#include <utility>

// Geometric product in Cl(3,2,1), DIM=64.
// out[n,k] = sum_a sign(a, a^k) * x[n,a] * y[n,a^k]
//
// ROUND 11 = R9's verified async-pipeline skeleton (global_load_lds with
// XOR-pre-swizzled global source, dbuf LDS, raw s_barrier, counted
// s_waitcnt vmcnt(8) never 0 mid-loop) + R10's low-pressure block-16 core:
//   k = 16q + j, a = 16m + i  =>  b = a^k = 16*(m^q) + (i^j)
// Per m-step the thread reads x block m and y block m^q from swizzled LDS
// (4+4 conflict-free ds_read_b128) and does 256 constant-sign FMAs.
// Peak live regs ~70 (acc16+xv16+yv16+temps): no spill (R9 died of spill
// at 160 live, NOT of its sync structure -- it passed correctness).
// q<2 waves skip m>=2 entirely (null-dim annihilation): 512 vs 1024 FMAs.
// T=4 tiles/block, grid 256 (1 block/CU), LDS 2x32 KB.

__host__ __device__ constexpr int popc6(int v) {
  int c = 0;
  for (int i = 0; i < 6; ++i) c += (v >> i) & 1;
  return c;
}

// Faithful to reference _cayley_tables(3,2,1): swap parity, (-1) per shared
// negative dim (bits 3,4), annihilation on shared null dim (bit 5).
__host__ __device__ constexpr float sign_ab(int a, int b) {
  int sw = 0;
  for (int bit = 0; bit < 6; ++bit)
    if ((a >> bit) & 1) sw += popc6(b & ((1 << bit) - 1));
  float s = (sw & 1) ? -1.0f : 1.0f;
  if (popc6(a & b & 0x18) & 1) s = -s;
  if (a & b & 0x20) s = 0.0f;
  return s;
}

// ---- compile-time FMA core: constant indices only (promotion-safe) ----
template <int Q, int M, int I, int J>
__device__ __forceinline__ void term(const float (&xv)[16], const float (&yv)[16],
                                     float (&acc)[16]) {
  constexpr int a = 16 * M + I;
  constexpr int k = 16 * Q + J;
  constexpr float sg = sign_ab(a, a ^ k);
  static_assert(sg != 0.0f, "zero terms must be excluded by M-list");
  if constexpr (sg > 0.0f) acc[J] = fmaf( xv[I], yv[I ^ J], acc[J]);
  else                     acc[J] = fmaf(-xv[I], yv[I ^ J], acc[J]);
}

template <int Q, int M, int I, int... J>
__device__ __forceinline__ void terms(const float (&xv)[16], const float (&yv)[16],
                                      float (&acc)[16], std::integer_sequence<int, J...>) {
  (term<Q, M, I, J>(xv, yv, acc), ...);
}

template <int Q, int M, int... I>
__device__ __forceinline__ void block_fma(const float (&xv)[16], const float (&yv)[16],
                                          float (&acc)[16], std::integer_sequence<int, I...>) {
  (terms<Q, M, I>(xv, yv, acc, std::make_integer_sequence<int, 16>{}), ...);
}

// One m-block: x granules (4M+u)^sw, y granules (4(M^Q)+u)^sw from the
// swizzled LDS tile (conflict-free b128: 8 lanes per bank-quad = floor),
// then 256 constant-sign FMAs.
template <int Q, int M>
__device__ __forceinline__ void group(const float4* __restrict__ buf, int rbase, int sw,
                                      float (&acc)[16]) {
  float xv[16], yv[16];
#pragma unroll
  for (int u = 0; u < 4; ++u) {
    const float4 fx = buf[rbase + ((4 * M + u) ^ sw)];
    const float4 fy = buf[1024 + rbase + ((4 * (M ^ Q) + u) ^ sw)];
    xv[4 * u + 0] = fx.x; xv[4 * u + 1] = fx.y; xv[4 * u + 2] = fx.z; xv[4 * u + 3] = fx.w;
    yv[4 * u + 0] = fy.x; yv[4 * u + 1] = fy.y; yv[4 * u + 2] = fy.z; yv[4 * u + 3] = fy.w;
  }
  block_fma<Q, M>(xv, yv, acc, std::make_integer_sequence<int, 16>{});
}

template <int Q>
__device__ __forceinline__ void core(const float4* __restrict__ buf, int lane,
                                     float (&acc)[16]) {
  const int rbase = lane * 16;
  const int sw = lane & 15;
  group<Q, 0>(buf, rbase, sw, acc);
  group<Q, 1>(buf, rbase, sw, acc);
  if constexpr (Q >= 2) {  // q<2: a>=32 annihilates (null dim) -> skip m=2,3
    group<Q, 2>(buf, rbase, sw, acc);
    group<Q, 3>(buf, rbase, sw, acc);
  }
}

typedef __attribute__((address_space(3))) unsigned int lds_u32;
typedef __attribute__((address_space(1))) const unsigned int glb_u32;

__device__ __forceinline__ void load16(const void* g, void* l) {
  __builtin_amdgcn_global_load_lds((glb_u32*)g, (lds_u32*)l, 16, 0, 0);
}

// Stage one 64x64 tile of x and y into `buf` (x: f4 [0,1024), y: +1024).
// Wave q stages rows [16q,16q+16): 4 gll each for x and y (8 in flight).
// Global source is XOR-pre-swizzled at 16B granularity; LDS dest linear:
// LDS[r][p] holds global granule p^(r&15).
__device__ __forceinline__ void stage(const float* __restrict__ xg,
                                      const float* __restrict__ yg,
                                      float4* __restrict__ buf, int lane, int q) {
#pragma unroll
  for (int i = 0; i < 4; ++i) {
    const int rb = 16 * q + 4 * i;            // wave-uniform row block (4 rows)
    const int r = rb + (lane >> 4);           // this lane's row
    const int gsw = (lane & 15) ^ (r & 15);   // swizzled source granule
    load16(xg + r * 64 + gsw * 4, (char*)(buf) + rb * 256);
    load16(yg + r * 64 + gsw * 4, (char*)(buf + 1024) + rb * 256);
  }
}

__global__ __launch_bounds__(256, 2)
void clgp_kernel(const float* __restrict__ xg, const float* __restrict__ yg,
                 float* __restrict__ og) {
  __shared__ float4 bufA[2048];  // 32 KB: x tile + y tile (swizzled granules)
  __shared__ float4 bufB[2048];

  const int t = threadIdx.x;
  const int lane = t & 63;
  const int q = t >> 6;                            // k-quarter (wave-uniform)
  const long base = (long)blockIdx.x * 4 * 4096;   // 4 tiles of 64x64 floats

  // prologue: stage tile 0 into bufA (8 loads/wave in flight)
  stage(xg + base, yg + base, bufA, lane, q);

#pragma unroll 1
  for (int u = 0; u < 4; ++u) {
    float4* bcur = (u & 1) ? bufB : bufA;
    float4* bnxt = (u & 1) ? bufA : bufB;

    // B0: prior iter's store-phase reads of bnxt done before re-staging it
    __builtin_amdgcn_s_barrier();
    if (u < 3) {
      const long nbase = base + (long)(u + 1) * 4096;
      stage(xg + nbase, yg + nbase, bnxt, lane, q);   // async, stays in flight
      asm volatile("s_waitcnt vmcnt(8)" ::: "memory"); // tile u landed; u+1 in flight
    } else {
      asm volatile("s_waitcnt vmcnt(0)" ::: "memory");
    }
    __builtin_amdgcn_sched_barrier(0);
    // B1: tile u visible to all waves
    __builtin_amdgcn_s_barrier();

    float acc[16];
#pragma unroll
    for (int i = 0; i < 16; ++i) acc[i] = 0.0f;
    switch (q) {  // wave-uniform
      case 0:  core<0>(bcur, lane, acc); break;
      case 1:  core<1>(bcur, lane, acc); break;
      case 2:  core<2>(bcur, lane, acc); break;
      default: core<3>(bcur, lane, acc); break;
    }
    __builtin_amdgcn_sched_barrier(0);
    // B2: all compute reads of bcur done -> bcur reusable as obuf
    __builtin_amdgcn_s_barrier();

    // transpose: thread (row=lane, quarter q) writes out[k=16q+j].
    // stride-65 rows: bank = (lane*65 + 16q + j)%32 -> 2-way over 64 lanes = free
    float* ob = (float*)bcur;  // 64x65 floats = 16.6 KB < 32 KB (dead buffer)
#pragma unroll
    for (int j = 0; j < 16; ++j) ob[lane * 65 + 16 * q + j] = acc[j];
    asm volatile("s_waitcnt lgkmcnt(0)" ::: "memory");
    __builtin_amdgcn_sched_barrier(0);
    // B3: transpose complete
    __builtin_amdgcn_s_barrier();

    float4* o4 = (float4*)(og + base + (long)u * 4096);
#pragma unroll
    for (int p = 0; p < 4; ++p) {
      const int v = t + p * 256;
      const int w = (v >> 4) * 65 + 4 * (v & 15);
      float4 o;
      o.x = ob[w + 0]; o.y = ob[w + 1]; o.z = ob[w + 2]; o.w = ob[w + 3];
      o4[v] = o;
    }
  }
}

extern "C" void kernel_launch(void* const* d_in, const int* in_sizes, int n_in,
                              void* d_out, int out_size, void* d_ws, size_t ws_size,
                              hipStream_t stream) {
  const float* x = (const float*)d_in[0];
  const float* y = (const float*)d_in[1];
  float* out = (float*)d_out;
  const int n_batch = in_sizes[0] / 64;        // 65536
  const int grid = n_batch / (64 * 4);         // 4 tiles/block -> 256 blocks
  clgp_kernel<<<grid, 256, 0, stream>>>(x, y, out);
}

// Round 12
// 17.926 us; speedup vs baseline: 3.1540x; 1.1177x over previous
//
#include <hip/hip_runtime.h>
#include <utility>

// Geometric product in Cl(3,2,1), DIM=64.
// out[n,k] = sum_a sign(a, a^k) * x[n,a] * y[n,a^k]
//
// ROUND 12: minimal-phase design combining every verified piece:
//   - block-16 decomposition (R10/R11): k=16q+j, a=16m+i => b=16(m^q)+(i^j)
//     thread (row, q) output = out[n][16q..16q+16) = CONTIGUOUS 64 B
//     -> direct register stores, NO transpose phase, NO obuf
//   - global_load_lds staging with XOR-pre-swizzled global source (R9/R11)
//   - conflict-spread b128 LDS reads of the swizzled tile (R11)
//   - ONE __syncthreads per block (its vmcnt0 drain is required anyway)
//   - 32 KB LDS/block -> 4 blocks/CU: cross-block load/compute/store overlap
//     (the R4 mechanism that beat every 1-block/CU pipeline)
// Per-CU budget: HBM 7.6us (floor) || LDS ~1.8us || VALU ~2.5us.

__host__ __device__ constexpr int popc6(int v) {
  int c = 0;
  for (int i = 0; i < 6; ++i) c += (v >> i) & 1;
  return c;
}

// Faithful to reference _cayley_tables(3,2,1): swap parity, (-1) per shared
// negative dim (bits 3,4), annihilation on shared null dim (bit 5).
__host__ __device__ constexpr float sign_ab(int a, int b) {
  int sw = 0;
  for (int bit = 0; bit < 6; ++bit)
    if ((a >> bit) & 1) sw += popc6(b & ((1 << bit) - 1));
  float s = (sw & 1) ? -1.0f : 1.0f;
  if (popc6(a & b & 0x18) & 1) s = -s;
  if (a & b & 0x20) s = 0.0f;
  return s;
}

// ---- compile-time FMA core: constant indices only (promotion-safe) ----
template <int Q, int M, int I, int J>
__device__ __forceinline__ void term(const float (&xv)[16], const float (&yv)[16],
                                     float (&acc)[16]) {
  constexpr int a = 16 * M + I;
  constexpr int k = 16 * Q + J;
  constexpr float sg = sign_ab(a, a ^ k);
  static_assert(sg != 0.0f, "zero terms must be excluded by M-list");
  if constexpr (sg > 0.0f) acc[J] = fmaf( xv[I], yv[I ^ J], acc[J]);
  else                     acc[J] = fmaf(-xv[I], yv[I ^ J], acc[J]);
}

template <int Q, int M, int I, int... J>
__device__ __forceinline__ void terms(const float (&xv)[16], const float (&yv)[16],
                                      float (&acc)[16], std::integer_sequence<int, J...>) {
  (term<Q, M, I, J>(xv, yv, acc), ...);
}

template <int Q, int M, int... I>
__device__ __forceinline__ void block_fma(const float (&xv)[16], const float (&yv)[16],
                                          float (&acc)[16], std::integer_sequence<int, I...>) {
  (terms<Q, M, I>(xv, yv, acc, std::make_integer_sequence<int, 16>{}), ...);
}

// One m-block: x granules (4M+u)^sw, y granules (4(M^Q)+u)^sw from the
// swizzled LDS tile (b128, XOR-spread across banks), then 256 FMAs.
template <int Q, int M>
__device__ __forceinline__ void group(const float4* __restrict__ buf, int rbase, int sw,
                                      float (&acc)[16]) {
  float xv[16], yv[16];
#pragma unroll
  for (int u = 0; u < 4; ++u) {
    const float4 fx = buf[rbase + ((4 * M + u) ^ sw)];
    const float4 fy = buf[1024 + rbase + ((4 * (M ^ Q) + u) ^ sw)];
    xv[4 * u + 0] = fx.x; xv[4 * u + 1] = fx.y; xv[4 * u + 2] = fx.z; xv[4 * u + 3] = fx.w;
    yv[4 * u + 0] = fy.x; yv[4 * u + 1] = fy.y; yv[4 * u + 2] = fy.z; yv[4 * u + 3] = fy.w;
  }
  block_fma<Q, M>(xv, yv, acc, std::make_integer_sequence<int, 16>{});
}

template <int Q>
__device__ __forceinline__ void core(const float4* __restrict__ buf, int lane,
                                     float (&acc)[16]) {
  const int rbase = lane * 16;
  const int sw = lane & 15;
  group<Q, 0>(buf, rbase, sw, acc);
  group<Q, 1>(buf, rbase, sw, acc);
  if constexpr (Q >= 2) {  // q<2: a>=32 annihilates (null dim) -> skip m=2,3
    group<Q, 2>(buf, rbase, sw, acc);
    group<Q, 3>(buf, rbase, sw, acc);
  }
}

typedef __attribute__((address_space(3))) unsigned int lds_u32;
typedef __attribute__((address_space(1))) const unsigned int glb_u32;

__device__ __forceinline__ void load16(const void* g, void* l) {
  __builtin_amdgcn_global_load_lds((glb_u32*)g, (lds_u32*)l, 16, 0, 0);
}

__global__ __launch_bounds__(256, 4)
void clgp_kernel(const float* __restrict__ xg, const float* __restrict__ yg,
                 float* __restrict__ og) {
  __shared__ float4 buf[2048];  // 32 KB: x tile [0,1024), y tile [1024,2048)

  const int t = threadIdx.x;
  const int lane = t & 63;
  const int q = t >> 6;                       // k-quarter (wave-uniform)
  const long base = (long)blockIdx.x * 4096;  // 64 rows * 64 floats

  // ---- stage: global_load_lds, XOR-pre-swizzled source, linear LDS dest.
  // Wave q stages rows [16q, 16q+16): LDS pos p of row r holds global
  // granule p^(r&15)  (read side undoes with the same XOR).
  const float* xb = xg + base;
  const float* yb = yg + base;
#pragma unroll
  for (int i = 0; i < 4; ++i) {
    const int rb = 16 * q + 4 * i;            // wave-uniform row block (4 rows)
    const int r = rb + (lane >> 4);           // this lane's row
    const int gsw = (lane & 15) ^ (r & 15);   // swizzled source granule
    load16(xb + r * 64 + gsw * 4, (char*)(buf) + rb * 256);
    load16(yb + r * 64 + gsw * 4, (char*)(buf + 1024) + rb * 256);
  }
  __syncthreads();  // drains vmcnt(0): tile visible to all waves

  float acc[16];
#pragma unroll
  for (int i = 0; i < 16; ++i) acc[i] = 0.0f;
  switch (q) {  // wave-uniform -> no divergence
    case 0:  core<0>(buf, lane, acc); break;
    case 1:  core<1>(buf, lane, acc); break;
    case 2:  core<2>(buf, lane, acc); break;
    default: core<3>(buf, lane, acc); break;
  }

  // ---- direct store: thread's k-quarter is contiguous 64 B; the four
  // q-waves tile each 256 B row -> L2 merges full lines. No transpose.
  float4* o4 = (float4*)(og + base + (long)lane * 64 + 16 * q);
#pragma unroll
  for (int j = 0; j < 4; ++j) {
    float4 o;
    o.x = acc[4 * j + 0]; o.y = acc[4 * j + 1]; o.z = acc[4 * j + 2]; o.w = acc[4 * j + 3];
    o4[j] = o;
  }
}

extern "C" void kernel_launch(void* const* d_in, const int* in_sizes, int n_in,
                              void* d_out, int out_size, void* d_ws, size_t ws_size,
                              hipStream_t stream) {
  const float* x = (const float*)d_in[0];
  const float* y = (const float*)d_in[1];
  float* out = (float*)d_out;
  const int n_batch = in_sizes[0] / 64;   // 65536
  const int grid = n_batch / 64;          // 1024 blocks, 256 threads, 4/CU
  clgp_kernel<<<grid, 256, 0, stream>>>(x, y, out);
}